// Round 5
// baseline (580.154 us; speedup 1.0000x reference)
//
#include <hip/hip_runtime.h>
#include <hip/hip_bf16.h>
#include <stdint.h>

#define B_DIM 16384
#define H_DIM 512
#define KTOT  1024   // I + H
#define NP    2048   // 4 gates * H

typedef __attribute__((ext_vector_type(8))) short short8;
typedef __attribute__((ext_vector_type(4))) float floatx4;
typedef __attribute__((ext_vector_type(16))) float floatx16;

static __device__ __forceinline__ unsigned short f2bf(float f) {
  unsigned int u = __float_as_uint(f);
  u += 0x7fffu + ((u >> 16) & 1u);
  return (unsigned short)(u >> 16);
}

static __device__ __forceinline__ short8 cvt8(floatx4 v0, floatx4 v1) {
  short8 o;
#pragma unroll
  for (int i = 0; i < 4; ++i) {
    o[i]     = (short)f2bf(v0[i]);
    o[i + 4] = (short)f2bf(v1[i]);
  }
  return o;
}

// ---------------------------------------------------------------------------
// Packed A (bf16) for 32x32x16 frags:
//   [bm(64)][kt(32)][wr(2)][m(4)][kk(2)][lane(64)][j(8)]
//   row = bm*256 + wr*128 + m*32 + (lane&31)
//   k   = kt*32 + kk*16 + (lane>>5)*8 + j     (k<512 -> x, else z)
// Tile (bm,kt) = 8192 ushorts = 16KB = LDS A-tile image (frag-linear).
// ---------------------------------------------------------------------------
__global__ __launch_bounds__(256) void pack_a_kernel(
    const float* __restrict__ x, const float* __restrict__ z,
    unsigned short* __restrict__ Ap) {
  int u    = blockIdx.x * 256 + threadIdx.x;
  int lane = u & 63;
  int kk   = (u >> 6) & 1;
  int m    = (u >> 7) & 3;
  int wr   = (u >> 9) & 1;
  int kt   = (u >> 10) & 31;
  int bm   = u >> 15;
  int row  = bm * 256 + wr * 128 + m * 32 + (lane & 31);
  int k    = kt * 32 + kk * 16 + ((lane >> 5) << 3);
  const float* src = (k < 512) ? (x + (uint64_t)row * 512 + k)
                               : (z + (uint64_t)row * 512 + (k - 512));
  floatx4 v0 = *reinterpret_cast<const floatx4*>(src);
  floatx4 v1 = *reinterpret_cast<const floatx4*>(src + 4);
  *reinterpret_cast<short8*>(Ap + (uint64_t)u * 8) = cvt8(v0, v1);
}

// ---------------------------------------------------------------------------
// Packed B (bf16) for 32x32x16 frags, gate-major fragments:
//   [bn(4)][kt(32)][wc(4)][g(4)][kk(2)][lane(64)][j(8)]
//   h = bn*128 + wc*32 + (lane&31); gate g
//   k = kt*32 + kk*16 + (lane>>5)*8 + j       (k<512 -> W_g, else U_g)
// Tile (bn,kt) = 16384 ushorts = 32KB = LDS B-tile image.
// ---------------------------------------------------------------------------
__global__ __launch_bounds__(256) void pack_w_kernel(
    const float* __restrict__ Wi, const float* __restrict__ Wf,
    const float* __restrict__ Wc, const float* __restrict__ Wo,
    const float* __restrict__ Ui, const float* __restrict__ Uf,
    const float* __restrict__ Uc, const float* __restrict__ Uo,
    unsigned short* __restrict__ Bp) {
  int u    = blockIdx.x * 256 + threadIdx.x;
  int lane = u & 63;
  int kk   = (u >> 6) & 1;
  int g    = (u >> 7) & 3;
  int wc   = (u >> 9) & 3;
  int kt   = (u >> 11) & 31;
  int bn   = u >> 16;
  int h    = bn * 128 + wc * 32 + (lane & 31);
  int k    = kt * 32 + kk * 16 + ((lane >> 5) << 3);
  const float* src;
  if (k < 512) {
    const float* W = (g == 0) ? Wi : (g == 1) ? Wf : (g == 2) ? Wc : Wo;
    src = W + (uint64_t)h * 512 + k;
  } else {
    const float* U = (g == 0) ? Ui : (g == 1) ? Uf : (g == 2) ? Uc : Uo;
    src = U + (uint64_t)h * 512 + (k - 512);
  }
  floatx4 v0 = *reinterpret_cast<const floatx4*>(src);
  floatx4 v1 = *reinterpret_cast<const floatx4*>(src + 4);
  *reinterpret_cast<short8*>(Bp + (uint64_t)u * 8) = cvt8(v0, v1);
}

// stage A-tile (16KB): 512 thr x 16B x 2;  stage B-tile (32KB): x 4
static __device__ __forceinline__ void stageA(const unsigned short* g,
                                              unsigned short* l, int tid) {
#pragma unroll
  for (int r = 0; r < 2; ++r)
    __builtin_amdgcn_global_load_lds(
        (const __attribute__((address_space(1))) void*)(g + r * 4096 + tid * 8),
        (__attribute__((address_space(3))) void*)(l + r * 4096 + tid * 8), 16, 0, 0);
}
static __device__ __forceinline__ void stageB(const unsigned short* g,
                                              unsigned short* l, int tid) {
#pragma unroll
  for (int r = 0; r < 4; ++r)
    __builtin_amdgcn_global_load_lds(
        (const __attribute__((address_space(1))) void*)(g + r * 4096 + tid * 8),
        (__attribute__((address_space(3))) void*)(l + r * 4096 + tid * 8), 16, 0, 0);
}

#define WAITBAR(S)                                  \
  asm volatile(S ::: "memory");                     \
  __builtin_amdgcn_sched_barrier(0);                \
  __builtin_amdgcn_s_barrier();                     \
  __builtin_amdgcn_sched_barrier(0);

// one K=16 sub-step: 8 frag reads (conflict-free: base + lane*16B), 16 MFMA
#define COMPUTE_KK(KK)                                                      \
  {                                                                         \
    short8 aF[4], bF[4];                                                    \
    _Pragma("unroll")                                                       \
    for (int m = 0; m < 4; ++m)                                             \
      aF[m] = *reinterpret_cast<const short8*>(aC + m * 1024 + (KK) * 512); \
    _Pragma("unroll")                                                       \
    for (int g = 0; g < 4; ++g)                                             \
      bF[g] = *reinterpret_cast<const short8*>(bC + g * 1024 + (KK) * 512); \
    __builtin_amdgcn_s_setprio(1);                                          \
    _Pragma("unroll")                                                       \
    for (int m = 0; m < 4; ++m)                                             \
      _Pragma("unroll")                                                     \
      for (int g = 0; g < 4; ++g)                                           \
        acc[m][g] = __builtin_amdgcn_mfma_f32_32x32x16_bf16(                \
            aF[m], bF[g], acc[m][g], 0, 0, 0);                              \
    __builtin_amdgcn_s_setprio(0);                                          \
  }

// ---------------------------------------------------------------------------
// GEMM M=16384 Np=2048 K=1024. Tile 256x512, BK=32, 8 waves (2wr x 4wc),
// each wave 128x128 = 4m x 4gate frags of 32x32x16 (acc = 256 VGPR).
// Grid = 256 = 1 block/CU, single round. Triple-buffered LDS (3 x 48KB):
// stage kt+2 during kt; per-tile wait = counted vmcnt(6) (6 loads/tile),
// vmcnt(0) only at tile 30. Single barrier per tile; compiler handles
// progressive lgkmcnt inside the tile (R3 structure, which beat R4's fences).
// LDS pipe/tile/CU: 128 ds_read_b128 ~1536 cyc < MFMA 256x8.07 ~2066 cyc.
// ---------------------------------------------------------------------------
__global__ __launch_bounds__(512, 1) void lstm_gemm_kernel(
    const unsigned short* __restrict__ Ap,
    const unsigned short* __restrict__ Bp,
    const float* __restrict__ z,
    const float* __restrict__ b_i, const float* __restrict__ b_f,
    const float* __restrict__ b_c, const float* __restrict__ b_o,
    float* __restrict__ out) {
  __shared__ unsigned short lds[73728];  // 144KB = 3 bufs x (A 16KB | B 32KB)

  int tid  = threadIdx.x;
  int bid  = blockIdx.x;
  int sw   = (bid & 7) * 32 + (bid >> 3);  // 256 % 8 == 0 -> bijective
  int bn   = sw & 3;     // 4 N-tiles (128 h * 4 gates)
  int bm   = sw >> 2;    // 64 M-tiles
  int lane = tid & 63;
  int wid  = tid >> 6;
  int wr   = wid >> 2;   // 0..1 -> 128 rows
  int wc   = wid & 3;    // 0..3 -> 32 h * 4 gates

  floatx16 acc[4][4];
#pragma unroll
  for (int m = 0; m < 4; ++m)
#pragma unroll
    for (int g = 0; g < 4; ++g)
#pragma unroll
      for (int r = 0; r < 16; ++r)
        acc[m][g][r] = 0.f;

  const unsigned short* gA = Ap + (uint64_t)bm * (32 * 8192);
  const unsigned short* gB = Bp + (uint64_t)bn * (32 * 16384);

  // prologue: stage tiles 0 and 1 (12 loads), need tile0 -> vmcnt(6)
  stageA(gA, lds, tid);
  stageB(gB, lds + 8192, tid);
  stageA(gA + 8192, lds + 24576, tid);
  stageB(gB + 16384, lds + 24576 + 8192, tid);
  asm volatile("s_waitcnt vmcnt(6)" ::: "memory");
  __builtin_amdgcn_sched_barrier(0);
  __builtin_amdgcn_s_barrier();
  __builtin_amdgcn_sched_barrier(0);

  int cur = 0;
#pragma unroll 1
  for (int kt = 0; kt < 30; ++kt) {
    int nxt2 = (cur >= 1) ? cur - 1 : 2;  // (cur+2)%3
    const unsigned short* aC = lds + cur * 24576 + wr * 4096 + lane * 8;
    const unsigned short* bC = lds + cur * 24576 + 8192 + wc * 4096 + lane * 8;
    unsigned short* aN = lds + nxt2 * 24576;
    unsigned short* bN = lds + nxt2 * 24576 + 8192;
    const unsigned short* gAs = gA + (kt + 2) * 8192;
    const unsigned short* gBs = gB + (kt + 2) * 16384;

    COMPUTE_KK(0)
    stageA(gAs, aN, tid);
    COMPUTE_KK(1)
    stageB(gBs, bN, tid);
    WAITBAR("s_waitcnt vmcnt(6)")
    cur = (cur == 2) ? 0 : cur + 1;
  }

  // tile 30: no staging; tile 31 must be fully landed -> vmcnt(0)
  {
    const unsigned short* aC = lds + cur * 24576 + wr * 4096 + lane * 8;
    const unsigned short* bC = lds + cur * 24576 + 8192 + wc * 4096 + lane * 8;
    COMPUTE_KK(0)
    COMPUTE_KK(1)
    WAITBAR("s_waitcnt vmcnt(0)")
    cur = (cur == 2) ? 0 : cur + 1;
  }
  // tile 31: last, no barrier
  {
    const unsigned short* aC = lds + cur * 24576 + wr * 4096 + lane * 8;
    const unsigned short* bC = lds + cur * 24576 + 8192 + wc * 4096 + lane * 8;
    COMPUTE_KK(0)
    COMPUTE_KK(1)
  }

  // ---- fused LSTM epilogue (lane-local: frag index g == gate)
  // 32x32 C/D map: col = lane&31, row = (r&3) + 8*(r>>2) + 4*(lane>>5)
  int h = bn * 128 + wc * 32 + (lane & 31);
  float vbi = b_i[h], vbf = b_f[h], vbc = b_c[h], vbo = b_o[h];
  int rb = bm * 256 + wr * 128 + ((lane >> 5) << 2);
  float* outH = out;
  float* outC = out + (uint64_t)B_DIM * H_DIM;
#pragma unroll
  for (int m = 0; m < 4; ++m) {
#pragma unroll
    for (int r = 0; r < 16; ++r) {
      int row = rb + m * 32 + (r & 3) + ((r >> 2) << 3);
      float pi = acc[m][0][r] + vbi;
      float pf = acc[m][1][r] + vbf;
      float pc = acc[m][2][r] + vbc;
      float po = acc[m][3][r] + vbo;
      float gi = 1.f / (1.f + __expf(-pi));
      float gf = 1.f / (1.f + __expf(-pf));
      float gc = 1.f - 2.f / (__expf(2.f * pc) + 1.f);  // tanh
      float go = 1.f / (1.f + __expf(-po));
      float zv = z[(uint64_t)row * H_DIM + h];
      float cn = gf * zv + gi * gc;
      float hn = go * (1.f - 2.f / (__expf(2.f * cn) + 1.f));
      outH[(uint64_t)row * H_DIM + h] = hn;
      outC[(uint64_t)row * H_DIM + h] = cn;
    }
  }
}

extern "C" void kernel_launch(void* const* d_in, const int* in_sizes, int n_in,
                              void* d_out, int out_size, void* d_ws, size_t ws_size,
                              hipStream_t stream) {
  const float* z  = (const float*)d_in[0];
  const float* x  = (const float*)d_in[1];
  const float* Wi = (const float*)d_in[2];
  const float* Wf = (const float*)d_in[3];
  const float* Wc = (const float*)d_in[4];
  const float* Wo = (const float*)d_in[5];
  const float* bi = (const float*)d_in[6];
  const float* bf = (const float*)d_in[7];
  const float* bc = (const float*)d_in[8];
  const float* bo = (const float*)d_in[9];
  const float* Ui = (const float*)d_in[10];
  const float* Uf = (const float*)d_in[11];
  const float* Uc = (const float*)d_in[12];
  const float* Uo = (const float*)d_in[13];

  unsigned short* Ap = (unsigned short*)d_ws;                          // 32 MB
  unsigned short* Bp = (unsigned short*)((char*)d_ws
                        + (size_t)B_DIM * KTOT * sizeof(unsigned short)); // +4 MB
  float* out = (float*)d_out;

  hipLaunchKernelGGL(pack_w_kernel, dim3((size_t)NP * KTOT / 8 / 256), dim3(256), 0, stream,
                     Wi, Wf, Wc, Wo, Ui, Uf, Uc, Uo, Bp);
  hipLaunchKernelGGL(pack_a_kernel, dim3((size_t)B_DIM * KTOT / 8 / 256), dim3(256), 0, stream,
                     x, z, Ap);
  hipLaunchKernelGGL(lstm_gemm_kernel, dim3(256), dim3(512), 0, stream,
                     Ap, Bp, z, bi, bf, bc, bo, out);
}

// Round 6
// 101.830 us; speedup vs baseline: 5.6973x; 5.6973x over previous
//
#include <hip/hip_runtime.h>
#include <hip/hip_bf16.h>
#include <stdint.h>

#define B_DIM 16384
#define H_DIM 512
#define KTOT  1024   // I + H
#define NP    2048   // 4 gates * H

typedef __attribute__((ext_vector_type(8))) short short8;
typedef __attribute__((ext_vector_type(4))) float floatx4;

static __device__ __forceinline__ unsigned short f2bf(float f) {
  unsigned int u = __float_as_uint(f);
  u += 0x7fffu + ((u >> 16) & 1u);
  return (unsigned short)(u >> 16);
}

static __device__ __forceinline__ short8 cvt8(floatx4 v0, floatx4 v1) {
  short8 o;
#pragma unroll
  for (int i = 0; i < 4; ++i) {
    o[i]     = (short)f2bf(v0[i]);
    o[i + 4] = (short)f2bf(v1[i]);
  }
  return o;
}

// ---------------------------------------------------------------------------
// Packed A (bf16), 16x16x32 frag-linear, BK=32 tiles:
//   [bm(64)][kt(32)][wr(2)][mh(2)][m4(4)][lane(64)][j(8)]
//   row = bm*256 + wr*128 + mh*64 + m4*16 + (lane&15)
//   k   = kt*32 + (lane>>4)*8 + j          (k<512 -> x, else z)
// Tile (bm,kt) = 8192 ushorts = 16KB = exact LDS A-tile image.
// ---------------------------------------------------------------------------
__global__ __launch_bounds__(256) void pack_a_kernel(
    const float* __restrict__ x, const float* __restrict__ z,
    unsigned short* __restrict__ Ap) {
  int u    = blockIdx.x * 256 + threadIdx.x;
  int lane = u & 63;
  int m4   = (u >> 6) & 3;
  int mh   = (u >> 8) & 1;
  int wr   = (u >> 9) & 1;
  int kt   = (u >> 10) & 31;
  int bm   = u >> 15;
  int row  = bm * 256 + wr * 128 + mh * 64 + m4 * 16 + (lane & 15);
  int k    = kt * 32 + ((lane >> 4) << 3);
  const float* src = (k < 512) ? (x + (uint64_t)row * 512 + k)
                               : (z + (uint64_t)row * 512 + (k - 512));
  floatx4 v0 = *reinterpret_cast<const floatx4*>(src);
  floatx4 v1 = *reinterpret_cast<const floatx4*>(src + 4);
  *reinterpret_cast<short8*>(Ap + (uint64_t)u * 8) = cvt8(v0, v1);
}

// ---------------------------------------------------------------------------
// Packed B (bf16), gate-major frags, BK=32 tiles:
//   [bn(8)][kt(32)][wc(4)][nh(2)][n2(2)][lane(64)][j(8)]
//   h = bn*64 + wc*16 + (lane&15); gate g = nh*2+n2
//   k = kt*32 + (lane>>4)*8 + j            (k<512 -> W_g, else U_g)
// Tile (bn,kt) = 8192 ushorts = 16KB = exact LDS B-tile image.
// ---------------------------------------------------------------------------
__global__ __launch_bounds__(256) void pack_w_kernel(
    const float* __restrict__ Wi, const float* __restrict__ Wf,
    const float* __restrict__ Wc, const float* __restrict__ Wo,
    const float* __restrict__ Ui, const float* __restrict__ Uf,
    const float* __restrict__ Uc, const float* __restrict__ Uo,
    unsigned short* __restrict__ Bp) {
  int u    = blockIdx.x * 256 + threadIdx.x;
  int lane = u & 63;
  int n2   = (u >> 6) & 1;
  int nh   = (u >> 7) & 1;
  int wc   = (u >> 8) & 3;
  int kt   = (u >> 10) & 31;
  int bn   = u >> 15;
  int g    = nh * 2 + n2;
  int h    = bn * 64 + wc * 16 + (lane & 15);
  int k    = kt * 32 + ((lane >> 4) << 3);
  const float* src;
  if (k < 512) {
    const float* W = (g == 0) ? Wi : (g == 1) ? Wf : (g == 2) ? Wc : Wo;
    src = W + (uint64_t)h * 512 + k;
  } else {
    const float* U = (g == 0) ? Ui : (g == 1) ? Uf : (g == 2) ? Uc : Uo;
    src = U + (uint64_t)h * 512 + (k - 512);
  }
  floatx4 v0 = *reinterpret_cast<const floatx4*>(src);
  floatx4 v1 = *reinterpret_cast<const floatx4*>(src + 4);
  *reinterpret_cast<short8*>(Bp + (uint64_t)u * 8) = cvt8(v0, v1);
}

// stage one 16KB tile: 512 threads x 16B x 2 instructions
static __device__ __forceinline__ void stage2(const unsigned short* g,
                                              unsigned short* l, int tid) {
  __builtin_amdgcn_global_load_lds(
      (const __attribute__((address_space(1))) void*)(g + tid * 8),
      (__attribute__((address_space(3))) void*)(l + tid * 8), 16, 0, 0);
  __builtin_amdgcn_global_load_lds(
      (const __attribute__((address_space(1))) void*)(g + 4096 + tid * 8),
      (__attribute__((address_space(3))) void*)(l + 4096 + tid * 8), 16, 0, 0);
}

#define WAITBAR(S)                                  \
  asm volatile(S ::: "memory");                     \
  __builtin_amdgcn_sched_barrier(0);                \
  __builtin_amdgcn_s_barrier();                     \
  __builtin_amdgcn_sched_barrier(0);

// one K-tile body: 12 ds_read_b128 (minimum for this wave shape), 32 MFMA,
// 4 global_load_lds staged 2 tiles ahead. Free interior (no fences) — the
// compiler pipelines reads ahead of MFMAs with progressive lgkmcnt (R3 won
// with this vs R4's rigid fences).
#define KTILE_BODY(DO_STAGE)                                                \
  {                                                                         \
    short8 aF[4], bF[4];                                                    \
    _Pragma("unroll")                                                       \
    for (int g = 0; g < 4; ++g)                                             \
      bF[g] = *reinterpret_cast<const short8*>(bC + g * 512);               \
    _Pragma("unroll")                                                       \
    for (int m4 = 0; m4 < 4; ++m4)                                          \
      aF[m4] = *reinterpret_cast<const short8*>(aC + m4 * 512);             \
    if (DO_STAGE) stage2(gAs, aN, tid);                                     \
    __builtin_amdgcn_s_setprio(1);                                          \
    _Pragma("unroll")                                                       \
    for (int m4 = 0; m4 < 4; ++m4)                                          \
      _Pragma("unroll")                                                     \
      for (int g = 0; g < 4; ++g)                                           \
        acc[m4][g] = __builtin_amdgcn_mfma_f32_16x16x32_bf16(               \
            aF[m4], bF[g], acc[m4][g], 0, 0, 0);                            \
    __builtin_amdgcn_s_setprio(0);                                          \
    _Pragma("unroll")                                                       \
    for (int m4 = 0; m4 < 4; ++m4)                                          \
      aF[m4] = *reinterpret_cast<const short8*>(aC + 2048 + m4 * 512);      \
    if (DO_STAGE) stage2(gBs, bN, tid);                                     \
    __builtin_amdgcn_s_setprio(1);                                          \
    _Pragma("unroll")                                                       \
    for (int m4 = 0; m4 < 4; ++m4)                                          \
      _Pragma("unroll")                                                     \
      for (int g = 0; g < 4; ++g)                                           \
        acc[4 + m4][g] = __builtin_amdgcn_mfma_f32_16x16x32_bf16(           \
            aF[m4], bF[g], acc[4 + m4][g], 0, 0, 0);                        \
    __builtin_amdgcn_s_setprio(0);                                          \
  }

// ---------------------------------------------------------------------------
// GEMM M=16384 Np=2048 K=1024. Tile 256x256, BK=32, 8 waves (2wr x 4wc),
// wave = 128 rows x 64 cols (16h x 4 gates); acc[8][4] = 128 regs.
// Triple-buffered LDS (3 x 32KB = 96KB), stage kt+2 during kt, ONE barrier
// per K-tile, steady-state wait vmcnt(4) (kt+2's 4 loads stay in flight).
// Reg budget: 128 acc + 48 frags + ~35 addr < 256 -> no spill (R5's bug).
// ---------------------------------------------------------------------------
__global__ __launch_bounds__(512, 2) void lstm_gemm_kernel(
    const unsigned short* __restrict__ Ap,
    const unsigned short* __restrict__ Bp,
    const float* __restrict__ z,
    const float* __restrict__ b_i, const float* __restrict__ b_f,
    const float* __restrict__ b_c, const float* __restrict__ b_o,
    float* __restrict__ out) {
  __shared__ unsigned short lds[49152];  // 96KB = 3 bufs x (A 16KB | B 16KB)

  int tid  = threadIdx.x;
  int bid  = blockIdx.x;
  int sw   = (bid & 7) * 64 + (bid >> 3);  // 512 % 8 == 0 -> bijective
  int bn   = sw & 7;     // 8 N-tiles (64 h * 4 gates)
  int bm   = sw >> 3;    // 64 M-tiles
  int lane = tid & 63;
  int wid  = tid >> 6;
  int wr   = wid >> 2;   // 0..1 -> 128 rows
  int wc   = wid & 3;    // 0..3 -> 16 h * 4 gates

  floatx4 acc[8][4];
#pragma unroll
  for (int m = 0; m < 8; ++m)
#pragma unroll
    for (int g = 0; g < 4; ++g)
      acc[m][g] = (floatx4){0.f, 0.f, 0.f, 0.f};

  const unsigned short* gA = Ap + (uint64_t)bm * (32 * 8192);
  const unsigned short* gB = Bp + (uint64_t)bn * (32 * 8192);

  // prologue: stage tiles 0,1 (8 loads); need tile0 -> vmcnt(4)
  stage2(gA, lds, tid);
  stage2(gB, lds + 8192, tid);
  stage2(gA + 8192, lds + 16384, tid);
  stage2(gB + 8192, lds + 16384 + 8192, tid);
  asm volatile("s_waitcnt vmcnt(4)" ::: "memory");
  __builtin_amdgcn_sched_barrier(0);
  __builtin_amdgcn_s_barrier();
  __builtin_amdgcn_sched_barrier(0);

  int cur = 0;
#pragma unroll 1
  for (int kt = 0; kt < 30; ++kt) {
    int nxt2 = (cur >= 1) ? cur - 1 : 2;  // (cur+2)%3
    const unsigned short* aC = lds + cur * 16384 + wr * 4096 + lane * 8;
    const unsigned short* bC = lds + cur * 16384 + 8192 + wc * 2048 + lane * 8;
    unsigned short* aN = lds + nxt2 * 16384;
    unsigned short* bN = aN + 8192;
    const unsigned short* gAs = gA + (kt + 2) * 8192;
    const unsigned short* gBs = gB + (kt + 2) * 8192;

    KTILE_BODY(true)
    WAITBAR("s_waitcnt vmcnt(4)")   // kt+1 landed; kt+2's 4 stay in flight
    cur = (cur == 2) ? 0 : cur + 1;
  }

  // tile 30: no staging; tile 31 must be fully landed
  {
    const unsigned short* aC = lds + cur * 16384 + wr * 4096 + lane * 8;
    const unsigned short* bC = lds + cur * 16384 + 8192 + wc * 2048 + lane * 8;
    unsigned short* aN = nullptr; unsigned short* bN = nullptr;
    const unsigned short* gAs = nullptr; const unsigned short* gBs = nullptr;
    KTILE_BODY(false)
    WAITBAR("s_waitcnt vmcnt(0)")
    cur = (cur == 2) ? 0 : cur + 1;
  }
  // tile 31: last, no barrier
  {
    const unsigned short* aC = lds + cur * 16384 + wr * 4096 + lane * 8;
    const unsigned short* bC = lds + cur * 16384 + 8192 + wc * 2048 + lane * 8;
    unsigned short* aN = nullptr; unsigned short* bN = nullptr;
    const unsigned short* gAs = nullptr; const unsigned short* gBs = nullptr;
    KTILE_BODY(false)
  }

  // ---- fused LSTM epilogue (lane-local: acc frag index g == gate)
  int h = bn * 64 + wc * 16 + (lane & 15);
  float vbi = b_i[h], vbf = b_f[h], vbc = b_c[h], vbo = b_o[h];
  int rbase = bm * 256 + wr * 128 + ((lane >> 4) << 2);
  float* outH = out;
  float* outC = out + (uint64_t)B_DIM * H_DIM;
#pragma unroll
  for (int m = 0; m < 8; ++m) {
#pragma unroll
    for (int j = 0; j < 4; ++j) {
      int r = rbase + m * 16 + j;
      float pi = acc[m][0][j] + vbi;
      float pf = acc[m][1][j] + vbf;
      float pc = acc[m][2][j] + vbc;
      float po = acc[m][3][j] + vbo;
      float gi = 1.f / (1.f + __expf(-pi));
      float gf = 1.f / (1.f + __expf(-pf));
      float gc = 1.f - 2.f / (__expf(2.f * pc) + 1.f);  // tanh
      float go = 1.f / (1.f + __expf(-po));
      float zv = z[(uint64_t)r * H_DIM + h];
      float cn = gf * zv + gi * gc;
      float hn = go * (1.f - 2.f / (__expf(2.f * cn) + 1.f));
      outH[(uint64_t)r * H_DIM + h] = hn;
      outC[(uint64_t)r * H_DIM + h] = cn;
    }
  }
}

extern "C" void kernel_launch(void* const* d_in, const int* in_sizes, int n_in,
                              void* d_out, int out_size, void* d_ws, size_t ws_size,
                              hipStream_t stream) {
  const float* z  = (const float*)d_in[0];
  const float* x  = (const float*)d_in[1];
  const float* Wi = (const float*)d_in[2];
  const float* Wf = (const float*)d_in[3];
  const float* Wc = (const float*)d_in[4];
  const float* Wo = (const float*)d_in[5];
  const float* bi = (const float*)d_in[6];
  const float* bf = (const float*)d_in[7];
  const float* bc = (const float*)d_in[8];
  const float* bo = (const float*)d_in[9];
  const float* Ui = (const float*)d_in[10];
  const float* Uf = (const float*)d_in[11];
  const float* Uc = (const float*)d_in[12];
  const float* Uo = (const float*)d_in[13];

  unsigned short* Ap = (unsigned short*)d_ws;                          // 32 MB
  unsigned short* Bp = (unsigned short*)((char*)d_ws
                        + (size_t)B_DIM * KTOT * sizeof(unsigned short)); // +4 MB
  float* out = (float*)d_out;

  hipLaunchKernelGGL(pack_w_kernel, dim3((size_t)NP * KTOT / 8 / 256), dim3(256), 0, stream,
                     Wi, Wf, Wc, Wo, Ui, Uf, Uc, Uo, Bp);
  hipLaunchKernelGGL(pack_a_kernel, dim3((size_t)B_DIM * KTOT / 8 / 256), dim3(256), 0, stream,
                     x, z, Ap);
  hipLaunchKernelGGL(lstm_gemm_kernel, dim3(512), dim3(512), 0, stream,
                     Ap, Bp, z, bi, bf, bc, bo, out);
}